// Round 6
// baseline (148.239 us; speedup 1.0000x reference)
//
#include <hip/hip_runtime.h>

// ---------------------------------------------------------------------------
// RMSNormSparse: out = weight * (mask?x:0) * rsqrt(mean((mask?x:0)^2) + eps)
// B=4, S=4096, D=4096. ALL TENSORS FP32; mask is fp32 0.0/1.0 (word != 0).
//
// Established by rounds 0-5:
//  - mask is fp32; it exactly fits L3 (FETCH ~= x only -> mask ~100% L3 hits).
//  - HBM floor traffic = x read (256 MiB) + out write (256 MiB) = 512 MiB.
//  - Round 5 (prefetch + manual barrier) == round 1 (no prefetch) at ~147 us:
//    VGPR_Count=52 proves the compiler SANK the prefetch loads past the
//    inline-asm barrier to the consume site (needs >=80 VGPRs if live).
//    The cross-barrier prefetch was never actually executed.
//
// Round-6 change (single variable): __builtin_amdgcn_sched_barrier(0)
//  (a) right after the prefetch-issue block -- machine scheduler cannot sink
//      the global loads below this point, so they issue BEFORE the reduce and
//      stay in flight across the manual barrier;
//  (b) right after s_barrier -- nothing hoists above the barrier (rule #18).
// Success check: VGPR_Count rises to ~80-104. Then dur tells us whether
// per-wave load latency (queueing) was the limiter or the memory system
// caps at ~3.6 TB/s HBM for this stream mix.
// ---------------------------------------------------------------------------

#define EPS_RMS 1e-5f

typedef float f32x4 __attribute__((ext_vector_type(4)));
typedef int i32x4 __attribute__((ext_vector_type(4)));

__global__ __launch_bounds__(256, 4) void rmsnorm_sparse_fast4096(
    const float* __restrict__ x,
    const int* __restrict__ mask,  // fp32 0.0/1.0 viewed as words; !=0 = keep
    const float* __restrict__ weight,
    float* __restrict__ out,
    int nrows, int rstride) {
    const int t = threadIdx.x;
    __shared__ float ws[2][4];

    // Loop-invariant weight row: loaded once per block, lives in registers.
    const f32x4* __restrict__ w4 = (const f32x4*)weight;
    f32x4 wv[4];
#pragma unroll
    for (int i = 0; i < 4; ++i) wv[i] = w4[t + 256 * i];

    const f32x4* __restrict__ x4 = (const f32x4*)x;
    const i32x4* __restrict__ m4 = (const i32x4*)mask;
    f32x4* __restrict__ o4 = (f32x4*)out;

    int r = blockIdx.x;
    if (r >= nrows) return;  // uniform per block (never true with our grid)

    // Preload first row (x + mask words).
    f32x4 xv[4];
    i32x4 mm[4];
    {
        const size_t b = (size_t)r * 1024u;
#pragma unroll
        for (int i = 0; i < 4; ++i) xv[i] = x4[b + t + 256 * i];
#pragma unroll
        for (int i = 0; i < 4; ++i) mm[i] = m4[b + t + 256 * i];
    }

    int parity = 0;
    for (;;) {
        const int rn = r + rstride;
        const bool has_next = rn < nrows;  // uniform per block

        // Prefetch next row. The sched_barrier below PINS these loads here:
        // round 5 proved that without it the scheduler sinks them past the
        // manual barrier to the consume site (VGPR_Count 52, no prefetch).
        f32x4 xn[4];
        i32x4 mn[4];
        if (has_next) {
            const size_t nb = (size_t)rn * 1024u;
#pragma unroll
            for (int i = 0; i < 4; ++i) xn[i] = x4[nb + t + 256 * i];
#pragma unroll
            for (int i = 0; i < 4; ++i) mn[i] = m4[nb + t + 256 * i];
        }
        __builtin_amdgcn_sched_barrier(0);  // loads may not sink below here

        // Masked values + sum of squares (v[] stays live through the store).
        float s = 0.f;
        f32x4 v[4];
#pragma unroll
        for (int i = 0; i < 4; ++i) {
            f32x4 a = xv[i];
            const i32x4 u = mm[i];
            a.x = (u.x != 0) ? a.x : 0.f;
            a.y = (u.y != 0) ? a.y : 0.f;
            a.z = (u.z != 0) ? a.z : 0.f;
            a.w = (u.w != 0) ? a.w : 0.f;
            v[i] = a;
            s += a.x * a.x + a.y * a.y + a.z * a.z + a.w * a.w;
        }
#pragma unroll
        for (int off = 1; off < 64; off <<= 1) s += __shfl_xor(s, off);

        if ((t & 63) == 0) ws[parity][t >> 6] = s;
        // Manual barrier: wait LDS traffic only -- do NOT drain vmcnt (the
        // prefetch). __syncthreads() would emit s_waitcnt vmcnt(0).
        asm volatile("s_waitcnt lgkmcnt(0)" ::: "memory");
        __builtin_amdgcn_s_barrier();
        __builtin_amdgcn_sched_barrier(0);  // nothing hoists above the barrier

        const float total =
            ws[parity][0] + ws[parity][1] + ws[parity][2] + ws[parity][3];
        const float scale = rsqrtf(total * (1.0f / 4096.0f) + EPS_RMS);

        const size_t ob = (size_t)r * 1024u;
#pragma unroll
        for (int i = 0; i < 4; ++i) {
            const f32x4 o = v[i] * scale * wv[i];
            __builtin_nontemporal_store(o, &o4[ob + t + 256 * i]);
        }

        if (!has_next) break;
        r = rn;
#pragma unroll
        for (int i = 0; i < 4; ++i) { xv[i] = xn[i]; mm[i] = mn[i]; }
        parity ^= 1;
    }
}

// Generic fallback for D != 4096 (fp32/int word mask; correctness only).
__global__ void rmsnorm_sparse_generic(const float* __restrict__ x,
                                       const int* __restrict__ mask,
                                       const float* __restrict__ weight,
                                       float* __restrict__ out, int D,
                                       int nrows) {
    const int t = threadIdx.x;
    const int lane = t & 63;
    const int wave = t >> 6;
    const int nw = (blockDim.x + 63) / 64;
    __shared__ float ws[16];

    for (int row = blockIdx.x; row < nrows; row += gridDim.x) {
        const size_t base = (size_t)row * (size_t)D;

        float s = 0.f;
        for (int d = t; d < D; d += blockDim.x) {
            float xv = x[base + d];
            float xm = (mask[base + d] != 0) ? xv : 0.f;
            s += xm * xm;
        }
#pragma unroll
        for (int off = 32; off > 0; off >>= 1) s += __shfl_down(s, off);
        if (lane == 0) ws[wave] = s;
        __syncthreads();
        float total = 0.f;
        for (int i = 0; i < nw; ++i) total += ws[i];
        const float scale = rsqrtf(total / (float)D + EPS_RMS);
        __syncthreads();  // protect ws before next iteration's writes

        for (int d = t; d < D; d += blockDim.x) {
            float xv = x[base + d];
            float xm = (mask[base + d] != 0) ? xv : 0.f;
            out[base + d] = weight[d] * xm * scale;
        }
    }
}

extern "C" void kernel_launch(void* const* d_in, const int* in_sizes, int n_in,
                              void* d_out, int out_size, void* d_ws,
                              size_t ws_size, hipStream_t stream) {
    const float* x = (const float*)d_in[0];
    const int* mask = (const int*)d_in[1];  // fp32 0/1 words; !=0 test
    const float* weight = (const float*)d_in[2];
    float* out = (float*)d_out;

    const int D = in_sizes[2];         // weight length
    const int rows = in_sizes[0] / D;  // B*S

    if (D == 4096) {
        const int blocks = rows < 2048 ? rows : 2048;
        rmsnorm_sparse_fast4096<<<blocks, 256, 0, stream>>>(x, mask, weight,
                                                            out, rows, blocks);
    } else {
        const int blocks = rows < 2048 ? rows : 2048;
        rmsnorm_sparse_generic<<<blocks, 256, 0, stream>>>(x, mask, weight,
                                                           out, D, rows);
    }
}